// Round 10
// baseline (285.617 us; speedup 1.0000x reference)
//
#include <hip/hip_runtime.h>

// PolyRPE attention, MI355X gfx950.
// prep (cvt + LDS-tiled transposes) -> QKV GEMM (LDS-FREE streaming: frags
// global->VGPR, L1/L2 serve reuse, 4 blocks/CU, no barriers, T1 XCD grid) ->
// fused flash attention (4 blocks/CU, P overlay, 1 barrier/tile) -> proj GEMM.
//
// Dims: B=16, N=577 (pad 640), C=768, h=12, d=64, K=768, 3C=2304.

using u16 = unsigned short;
using u32 = unsigned int;

typedef __bf16 bf16x8 __attribute__((ext_vector_type(8)));
typedef float f32x4 __attribute__((ext_vector_type(4)));

__device__ inline u16 f2bf(float f) {
    u32 u = __builtin_bit_cast(u32, f);
    u32 r = u + 0x7fffu + ((u >> 16) & 1u);   // RNE
    return (u16)(r >> 16);
}
__device__ inline float bf2f(u16 x) {
    return __builtin_bit_cast(float, (u32)x << 16);
}

__device__ inline f32x4 mfma16(bf16x8 a, bf16x8 b, f32x4 c) {
    return __builtin_amdgcn_mfma_f32_16x16x32_bf16(a, b, c, 0, 0, 0);
}

__device__ inline float fexp2(float x) { return __builtin_amdgcn_exp2f(x); }

// bijective XCD chunk remap (m204)
__device__ inline int xcd_remap(int bid, int nwg) {
    const int q = nwg >> 3, r = nwg & 7;
    const int xcd = bid & 7, idx = bid >> 3;
    return (xcd < r ? xcd * (q + 1) : r * (q + 1) + (xcd - r) * q) + idx;
}

// 16-lane (DPP-row) reductions.
__device__ inline float dpp_max16(float v) {
    int x;
    x = __builtin_amdgcn_update_dpp(0, __builtin_bit_cast(int, v), 0xB1, 0xF, 0xF, true);
    v = fmaxf(v, __builtin_bit_cast(float, x));
    x = __builtin_amdgcn_update_dpp(0, __builtin_bit_cast(int, v), 0x4E, 0xF, 0xF, true);
    v = fmaxf(v, __builtin_bit_cast(float, x));
    x = __builtin_amdgcn_update_dpp(0, __builtin_bit_cast(int, v), 0x124, 0xF, 0xF, true);
    v = fmaxf(v, __builtin_bit_cast(float, x));
    x = __builtin_amdgcn_update_dpp(0, __builtin_bit_cast(int, v), 0x128, 0xF, 0xF, true);
    v = fmaxf(v, __builtin_bit_cast(float, x));
    return v;
}
__device__ inline float dpp_sum16(float v) {
    int x;
    x = __builtin_amdgcn_update_dpp(0, __builtin_bit_cast(int, v), 0xB1, 0xF, 0xF, true);
    v += __builtin_bit_cast(float, x);
    x = __builtin_amdgcn_update_dpp(0, __builtin_bit_cast(int, v), 0x4E, 0xF, 0xF, true);
    v += __builtin_bit_cast(float, x);
    x = __builtin_amdgcn_update_dpp(0, __builtin_bit_cast(int, v), 0x124, 0xF, 0xF, true);
    v += __builtin_bit_cast(float, x);
    x = __builtin_amdgcn_update_dpp(0, __builtin_bit_cast(int, v), 0x128, 0xF, 0xF, true);
    v += __builtin_bit_cast(float, x);
    return v;
}

// ---------------- prep ----------------
// blocks 0..575: LDS-tiled 64x64 transposes (432 wqkv + 144 wprj)
// blocks 576..2047: x fp32 -> bf16 (vectorized)
__global__ void k_prep(const float* __restrict__ x, const float* __restrict__ Wq,
                       const float* __restrict__ Wp, u16* __restrict__ xb,
                       u16* __restrict__ wqkv, u16* __restrict__ wprj) {
    const int bid = blockIdx.x;
    const int t = threadIdx.x;
    if (bid < 576) {
        __shared__ float tile[64][65];
        const float* src;
        u16* dst;
        int C, rt, ct;
        if (bid < 432) { src = Wq; dst = wqkv; C = 2304; rt = bid / 36; ct = bid % 36; }
        else { const int b2 = bid - 432; src = Wp; dst = wprj; C = 768; rt = b2 / 12; ct = b2 % 12; }
        const int row0 = rt * 64, col0 = ct * 64;
#pragma unroll
        for (int it = 0; it < 4; ++it) {
            const int row = it * 16 + (t >> 4);
            const float4 v = *(const float4*)&src[(size_t)(row0 + row) * C + col0 + (t & 15) * 4];
            tile[row][(t & 15) * 4 + 0] = v.x;
            tile[row][(t & 15) * 4 + 1] = v.y;
            tile[row][(t & 15) * 4 + 2] = v.z;
            tile[row][(t & 15) * 4 + 3] = v.w;
        }
        __syncthreads();
#pragma unroll
        for (int it = 0; it < 4; ++it) {
            const int oc = it * 16 + (t >> 4);     // input col = output row
            const int orr = (t & 15) * 4;          // input row = output col
            ushort4 o;
            o.x = f2bf(tile[orr + 0][oc]);
            o.y = f2bf(tile[orr + 1][oc]);
            o.z = f2bf(tile[orr + 2][oc]);
            o.w = f2bf(tile[orr + 3][oc]);
            *(ushort4*)&dst[(size_t)(col0 + oc) * 768 + row0 + orr] = o;
        }
    } else {
        const int n4 = 9232 * 768 / 4;
        const int stride = (2048 - 576) * 256;
        for (int i = (bid - 576) * 256 + t; i < n4; i += stride) {
            float4 v = ((const float4*)x)[i];
            ushort4 o;
            o.x = f2bf(v.x); o.y = f2bf(v.y); o.z = f2bf(v.z); o.w = f2bf(v.w);
            ((ushort4*)xb)[i] = o;
        }
    }
}

// ---------------- streaming GEMM (no LDS, no barriers) ----------------------
// C[M x N] = A[M x 768] * Bw^T, Bw [N][768] bf16. Block 128x128, 4 waves 2x2,
// wave tile 64x64. Fragments loaded global->VGPR each K-step: a wave reads
// 16 rows x 64B contiguous per frag (full cache lines); L1 serves the 2x
// intra-block reuse, XCD-chunked L2 holds the B panel + streaming A strip.
// MODE 0: QKV scatter -> Q/K [bh][640][64], Vt [bh][64][640]; MODE 1: fp32+bias.
template <int MODE, int NB>
__launch_bounds__(256, 4)
__global__ void k_gemm(const u16* __restrict__ A, const u16* __restrict__ Bw,
                       u16* __restrict__ q_out, u16* __restrict__ k_out,
                       u16* __restrict__ v_out,
                       float* __restrict__ f_out, const float* __restrict__ bias) {
    constexpr int NT = 24;                    // 768/32
    constexpr int M = 9232;
    const int wgid = xcd_remap(blockIdx.x, gridDim.x);
    const int mbase = (wgid / NB) * 128;
    const int nbase = (wgid - (wgid / NB) * NB) * 128;
    const int t = threadIdx.x;
    const int lane = t & 63, w = t >> 6;
    const int lr = lane & 15, lg = lane >> 4;
    const int wrow = (w >> 1) * 64, wcol = (w & 1) * 64;
    // per-lane fragment base pointers (row = tile row + lr, k = lg*8)
    const u16* Ap = A + (size_t)(mbase + wrow + lr) * 768 + lg * 8;
    const u16* Bp = Bw + (size_t)(nbase + wcol + lr) * 768 + lg * 8;
    f32x4 acc[4][4] = {};

#pragma unroll 1
    for (int kt = 0; kt < NT; ++kt) {
        const int ko = kt * 32;
        bf16x8 af[4], bv[4];
#pragma unroll
        for (int i = 0; i < 4; ++i)
            af[i] = *(const bf16x8*)(Ap + i * (16 * 768) + ko);
#pragma unroll
        for (int j = 0; j < 4; ++j)
            bv[j] = *(const bf16x8*)(Bp + j * (16 * 768) + ko);
        __builtin_amdgcn_s_setprio(1);
#pragma unroll
        for (int i = 0; i < 4; ++i)
#pragma unroll
            for (int j = 0; j < 4; ++j)
                acc[i][j] = mfma16(af[i], bv[j], acc[i][j]);
        __builtin_amdgcn_s_setprio(0);
    }

#pragma unroll
    for (int i = 0; i < 4; ++i) {
#pragma unroll
        for (int j = 0; j < 4; ++j) {
            const int col = nbase + wcol + j * 16 + lr;
#pragma unroll
            for (int r = 0; r < 4; ++r) {
                const int row = mbase + wrow + i * 16 + 4 * lg + r;
                if (row < M) {
                    if (MODE == 0) {
                        const int bb = row / 577;
                        const int nn = row - bb * 577;
                        const int tt = col / 768;
                        const int rem = col - tt * 768;
                        const int hh = rem >> 6, dd = rem & 63;
                        const size_t bh = (size_t)bb * 12 + hh;
                        const u16 val = f2bf(acc[i][j][r]);
                        if (tt == 0)      q_out[(bh * 640 + nn) * 64 + dd] = val;
                        else if (tt == 1) k_out[(bh * 640 + nn) * 64 + dd] = val;
                        else              v_out[(bh * 64 + dd) * 640 + nn] = val;
                    } else {
                        f_out[(size_t)row * 768 + col] = acc[i][j][r] + bias[col];
                    }
                }
            }
        }
    }
}

// ---------------- fused attention (q rows 0..575) ----------------
// 33 KB LDS -> 4 blocks/CU. P overlays Vl[cur^1] (dead V buffer); V staging
// rows are wave-owned so post-PV stores only touch the wave's consumed P.
__launch_bounds__(256, 4)
__global__ void k_attn(const u16* __restrict__ Qg, const u16* __restrict__ Kg,
                       const u16* __restrict__ Vtg, const float* __restrict__ coef,
                       u16* __restrict__ Og) {
    const int wgid = xcd_remap(blockIdx.x, gridDim.x);   // 1728 = 8*216 exact
    const int bh = wgid / 9;            // consecutive wgids share bh (XCD-local K/V)
    const int qt = wgid - bh * 9;       // 0..8
    const int b = bh / 12, h = bh - b * 12;
    const int t = threadIdx.x;
    const int lane = t & 63, w = t >> 6;
    const int lr = lane & 15, lg = lane >> 4;
    __shared__ alignas(16) u16 Kl[2][4096];
    __shared__ alignas(16) u16 Vl[2][4096];
    __shared__ float lut[48];

    {   // LUT: poly(dist)*log2e for dist<=46; lut[47]=0 catches CLS sentinels
        const float l2e = 1.4426950408889634f;
        const float c0 = coef[h * 4 + 0] * l2e, c1 = coef[h * 4 + 1] * l2e,
                    c2 = coef[h * 4 + 2] * l2e, c3 = coef[h * 4 + 3] * l2e;
        if (t < 48) {
            const float d = (float)t;
            lut[t] = (t <= 46) ? (((c3 * d + c2) * d + c1) * d + c0) : 0.f;
        }
    }

    const int qrow0 = qt * 64 + w * 16;
    const u16* qp = Qg + ((size_t)bh * 640 + qrow0 + lr) * 64;
    const bf16x8 qa0 = *(const bf16x8*)(qp + lg * 8);
    const bf16x8 qa1 = *(const bf16x8*)(qp + 32 + lg * 8);

    float gi[4], gj[4];
#pragma unroll
    for (int r = 0; r < 4; ++r) {
        const int n = qrow0 + 4 * lg + r;
        if (n == 0) { gi[r] = 100.f; gj[r] = 0.f; }
        else {
            const int nm1 = n - 1;
            const int qi = nm1 / 24;
            gi[r] = (float)qi;
            gj[r] = (float)(nm1 - qi * 24);
        }
    }

    float M[4], L[4];
#pragma unroll
    for (int r = 0; r < 4; ++r) { M[r] = -3e38f; L[r] = 0.f; }
    f32x4 acco[4] = {};
    const float scale2 = 0.125f * 1.4426950408889634f;
    const int ch0 = ((lg ^ (lr & 7))) * 8;      // swizzled read chunk (elems)

    const u16* Ksb = Kg + (size_t)bh * 640 * 64;
    const u16* Vsb = Vtg + (size_t)bh * 64 * 640;
    // K staging: rows t>>3 (any order; Kl[cur^1] unread this tile)
    const int pr0 = t >> 3, pc0 = t & 7;
    const int pr1 = (256 + t) >> 3, pc1 = (256 + t) & 7;
    const int kd0 = pr0 * 64 + ((pc0 ^ (pr0 & 7)) * 8);
    const int kd1 = pr1 * 64 + ((pc1 ^ (pr1 & 7)) * 8);
    // V staging: wave-owned rows (wave w -> rows 16w..16w+15)
    const int vr0 = 16 * w + (lane >> 3), vc = lane & 7;
    const int vr1 = vr0 + 8;
    const int vd0 = vr0 * 64 + ((vc ^ (vr0 & 7)) * 8);
    const int vd1 = vr1 * 64 + ((vc ^ (vr1 & 7)) * 8);

    {   // prologue: tile 0 -> regs -> LDS buf 0
        uint4 k0 = *(const uint4*)(Ksb + pr0 * 64 + pc0 * 8);
        uint4 k1 = *(const uint4*)(Ksb + pr1 * 64 + pc1 * 8);
        uint4 v0 = *(const uint4*)(Vsb + (size_t)vr0 * 640 + vc * 8);
        uint4 v1 = *(const uint4*)(Vsb + (size_t)vr1 * 640 + vc * 8);
        *(uint4*)(&Kl[0][kd0]) = k0;
        *(uint4*)(&Kl[0][kd1]) = k1;
        *(uint4*)(&Vl[0][vd0]) = v0;
        *(uint4*)(&Vl[0][vd1]) = v1;
    }
    __syncthreads();
    int cur = 0;

    for (int kt = 0; kt < 9; ++kt) {
        // issue next K/V tile's loads early (incl. tail tile 9)
        const u16* Ks = Ksb + (size_t)(kt + 1) * 64 * 64;
        const u16* Vs = Vsb + (size_t)(kt + 1) * 64;
        const uint4 nk0 = *(const uint4*)(Ks + pr0 * 64 + pc0 * 8);
        const uint4 nk1 = *(const uint4*)(Ks + pr1 * 64 + pc1 * 8);
        const uint4 nv0 = *(const uint4*)(Vs + (size_t)vr0 * 640 + vc * 8);
        const uint4 nv1 = *(const uint4*)(Vs + (size_t)vr1 * 640 + vc * 8);

        const u16* Kc = &Kl[cur][0];
        const u16* Vc = &Vl[cur][0];
        u16* pw = &Vl[cur ^ 1][w * 1024];    // P overlay: wave-owned 16x64

        // S = Q K^T
        f32x4 sac[4];
        __builtin_amdgcn_s_setprio(1);
#pragma unroll
        for (int cb = 0; cb < 4; ++cb) {
            const int row = cb * 16 + lr;
            const bf16x8 kb0 = *(const bf16x8*)(Kc + row * 64 + ch0);
            const bf16x8 kb1 = *(const bf16x8*)(Kc + row * 64 + (ch0 ^ 32));
            f32x4 z = {};
            z = mfma16(qa0, kb0, z);
            sac[cb] = mfma16(qa1, kb1, z);
        }
        __builtin_amdgcn_s_setprio(0);

        float s[4][4], tm[4];
#pragma unroll
        for (int r = 0; r < 4; ++r) tm[r] = -3e38f;
#pragma unroll
        for (int cb = 0; cb < 4; ++cb) {
            const int m = kt * 64 + cb * 16 + lr;
            float ci, cj;
            if (m == 0) { ci = 200.f; cj = 0.f; }
            else {
                const int mm1 = m - 1;
                const int pi = mm1 / 24;
                ci = (float)pi;
                cj = (float)(mm1 - pi * 24);
            }
#pragma unroll
            for (int r = 0; r < 4; ++r) {
                const float df = fabsf(gi[r] - ci) + fabsf(gj[r] - cj);
                const int idx = min((int)df, 47);
                const float v = fmaf(sac[cb][r], scale2, lut[idx]);
                s[cb][r] = v;
                tm[r] = fmaxf(tm[r], v);
            }
        }
#pragma unroll
        for (int r = 0; r < 4; ++r) tm[r] = dpp_max16(tm[r]);

        float over = tm[0] - M[0];
        over = fmaxf(over, tm[1] - M[1]);
        over = fmaxf(over, tm[2] - M[2]);
        over = fmaxf(over, tm[3] - M[3]);
        if (__any(over > 11.5f)) {
#pragma unroll
            for (int r = 0; r < 4; ++r) {
                const float Mn = fmaxf(M[r], tm[r]);
                const float a = fexp2(M[r] - Mn);
                L[r] *= a;
                acco[0][r] *= a; acco[1][r] *= a;
                acco[2][r] *= a; acco[3][r] *= a;
                M[r] = Mn;
            }
        }

        // P -> overlay (swizzled): row'=4lg+r, chunk=2cb+(lr>>3), elem=lr&7
#pragma unroll
        for (int cb = 0; cb < 4; ++cb)
#pragma unroll
            for (int r = 0; r < 4; ++r) {
                const float p = fexp2(s[cb][r] - M[r]);
                L[r] += p;
                const int rw = 4 * lg + r;
                pw[rw * 64 + (((2 * cb + (lr >> 3)) ^ (rw & 7)) * 8) + (lr & 7)] = f2bf(p);
            }
        const bf16x8 pa0 = *(const bf16x8*)(pw + lr * 64 + ch0);
        const bf16x8 pa1 = *(const bf16x8*)(pw + lr * 64 + (ch0 ^ 32));
        __builtin_amdgcn_s_setprio(1);
#pragma unroll
        for (int f = 0; f < 4; ++f) {
            const int vrow = f * 16 + lr;
            const bf16x8 vb0 = *(const bf16x8*)(Vc + vrow * 64 + ch0);
            const bf16x8 vb1 = *(const bf16x8*)(Vc + vrow * 64 + (ch0 ^ 32));
            acco[f] = mfma16(pa0, vb0, acco[f]);
            acco[f] = mfma16(pa1, vb1, acco[f]);
        }
        __builtin_amdgcn_s_setprio(0);

        // land prefetched tile: K anywhere in Kl[cur^1] (unread); V only into
        // this wave's own rows (its P was consumed above; per-wave DS order)
        *(uint4*)(&Kl[cur ^ 1][kd0]) = nk0;
        *(uint4*)(&Kl[cur ^ 1][kd1]) = nk1;
        *(uint4*)(&Vl[cur ^ 1][vd0]) = nv0;
        *(uint4*)(&Vl[cur ^ 1][vd1]) = nv1;
        __syncthreads();
        cur ^= 1;
    }

    {   // ---- peeled tail tile (kt=9): only key m=576 (cb=0, lr==0) valid ----
        const u16* Kc = &Kl[cur][0];
        const u16* Vc = &Vl[cur][0];
        u16* pw = &Vl[cur ^ 1][w * 1024];
        const bf16x8 kb0 = *(const bf16x8*)(Kc + lr * 64 + ch0);
        const bf16x8 kb1 = *(const bf16x8*)(Kc + lr * 64 + (ch0 ^ 32));
        f32x4 z = {};
        z = mfma16(qa0, kb0, z);
        const f32x4 sac0 = mfma16(qa1, kb1, z);

        float s0[4], tm[4];
#pragma unroll
        for (int r = 0; r < 4; ++r) {
            const float df = fabsf(gi[r] - 23.f) + fabsf(gj[r] - 23.f);
            float v = fmaf(sac0[r], scale2, lut[min((int)df, 47)]);
            v = (lr == 0) ? v : -1e30f;
            s0[r] = v;
            tm[r] = dpp_max16(v);
        }
        float over = tm[0] - M[0];
        over = fmaxf(over, tm[1] - M[1]);
        over = fmaxf(over, tm[2] - M[2]);
        over = fmaxf(over, tm[3] - M[3]);
        if (__any(over > 11.5f)) {
#pragma unroll
            for (int r = 0; r < 4; ++r) {
                const float Mn = fmaxf(M[r], tm[r]);
                const float a = fexp2(M[r] - Mn);
                L[r] *= a;
                acco[0][r] *= a; acco[1][r] *= a;
                acco[2][r] *= a; acco[3][r] *= a;
                M[r] = Mn;
            }
        }
#pragma unroll
        for (int cb = 0; cb < 4; ++cb)
#pragma unroll
            for (int r = 0; r < 4; ++r) {
                const float p = (cb == 0) ? fexp2(s0[r] - M[r]) : 0.f;
                L[r] += p;
                const int rw = 4 * lg + r;
                pw[rw * 64 + (((2 * cb + (lr >> 3)) ^ (rw & 7)) * 8) + (lr & 7)] = f2bf(p);
            }
        const bf16x8 pa0 = *(const bf16x8*)(pw + lr * 64 + ch0);
#pragma unroll
        for (int f = 0; f < 4; ++f) {
            const int vrow = f * 16 + lr;
            const bf16x8 vb0 = *(const bf16x8*)(Vc + vrow * 64 + ch0);
            acco[f] = mfma16(pa0, vb0, acco[f]);
        }
    }

    float inv[4];
#pragma unroll
    for (int r = 0; r < 4; ++r) inv[r] = __builtin_amdgcn_rcpf(dpp_sum16(L[r]));
#pragma unroll
    for (int f = 0; f < 4; ++f)
#pragma unroll
        for (int r = 0; r < 4; ++r) {
            const int n = qrow0 + 4 * lg + r;     // <= 575, always valid
            Og[((size_t)b * 577 + n) * 768 + h * 64 + f * 16 + lr] =
                f2bf(acco[f][r] * inv[r]);
        }
}

// ---------------- attention for the single leftover row n=576 ----------------
__launch_bounds__(256)
__global__ void k_attn_last(const u16* __restrict__ Qg, const u16* __restrict__ Kg,
                            const u16* __restrict__ Vtg, const float* __restrict__ coef,
                            u16* __restrict__ Og) {
    const int bh = blockIdx.x;
    const int b = bh / 12, h = bh - b * 12;
    const int t = threadIdx.x;
    const int lane = t & 63, w = t >> 6;
    __shared__ float qs[64];
    __shared__ float ps[640];
    __shared__ float red[4];
    __shared__ float opart[4][64];
    const float l2e = 1.4426950408889634f;
    const float c0 = coef[h * 4 + 0] * l2e, c1 = coef[h * 4 + 1] * l2e,
                c2 = coef[h * 4 + 2] * l2e, c3 = coef[h * 4 + 3] * l2e;
    const float scale2 = 0.125f * l2e;

    if (t < 64) qs[t] = bf2f(Qg[((size_t)bh * 640 + 576) * 64 + t]);
    __syncthreads();

    float sv[3];
#pragma unroll
    for (int u = 0; u < 3; ++u) {
        const int k = t + u * 256;
        float s = -3e38f;
        if (k < 577) {
            const u16* kp = Kg + ((size_t)bh * 640 + k) * 64;
            float acc = 0.f;
            for (int j = 0; j < 64; ++j) acc += qs[j] * bf2f(kp[j]);
            float rv = 0.f;
            if (k >= 1) {
                const int km1 = k - 1;
                const int ki = km1 / 24;
                const float d = fabsf(23.f - (float)ki) + fabsf(23.f - (float)(km1 - ki * 24));
                rv = ((c3 * d + c2) * d + c1) * d + c0;
            }
            s = fmaf(acc, scale2, rv);
        }
        sv[u] = s;
    }
    float v = fmaxf(fmaxf(sv[0], sv[1]), sv[2]);
    v = fmaxf(v, __shfl_xor(v, 1));  v = fmaxf(v, __shfl_xor(v, 2));
    v = fmaxf(v, __shfl_xor(v, 4));  v = fmaxf(v, __shfl_xor(v, 8));
    v = fmaxf(v, __shfl_xor(v, 16)); v = fmaxf(v, __shfl_xor(v, 32));
    if (lane == 0) red[w] = v;
    __syncthreads();
    const float Mx = fmaxf(fmaxf(red[0], red[1]), fmaxf(red[2], red[3]));

    float lsum = 0.f;
#pragma unroll
    for (int u = 0; u < 3; ++u) {
        const int k = t + u * 256;
        const float p = (k < 577) ? fexp2(sv[u] - Mx) : 0.f;
        if (k < 640) ps[k] = p;
        lsum += p;
    }
    lsum += __shfl_xor(lsum, 1);  lsum += __shfl_xor(lsum, 2);
    lsum += __shfl_xor(lsum, 4);  lsum += __shfl_xor(lsum, 8);
    lsum += __shfl_xor(lsum, 16); lsum += __shfl_xor(lsum, 32);
    __syncthreads();
    if (lane == 0) red[w] = lsum;
    __syncthreads();
    const float Lx = red[0] + red[1] + red[2] + red[3];

    const int d = t & 63, qd = t >> 6;
    const u16* vp = Vtg + ((size_t)bh * 64 + d) * 640;
    float o = 0.f;
    for (int k = qd * 160; k < qd * 160 + 160; ++k) o += ps[k] * bf2f(vp[k]);
    opart[qd][d] = o;
    __syncthreads();
    if (t < 64) {
        const float oo = (opart[0][t] + opart[1][t] + opart[2][t] + opart[3][t]) / Lx;
        Og[((size_t)b * 577 + 576) * 768 + h * 64 + t] = f2bf(oo);
    }
}

// ---------------- launch ----------------
extern "C" void kernel_launch(void* const* d_in, const int* in_sizes, int n_in,
                              void* d_out, int out_size, void* d_ws, size_t ws_size,
                              hipStream_t stream) {
    const float* x      = (const float*)d_in[0];
    const float* W_qkv  = (const float*)d_in[1];
    const float* W_proj = (const float*)d_in[2];
    const float* b_proj = (const float*)d_in[3];
    const float* coef   = (const float*)d_in[4];
    float* out = (float*)d_out;
    char* ws = (char*)d_ws;

    // ws layout with lifetime aliasing (66.1 MB total):
    //   xb : live prep..gemm0  |  Og : live attn..gemm1 (ALIASES xb)
    u16* xb   = (u16*)(ws + 0);                        // 14,180,352
    u16* Og   = (u16*)(ws + 0);                        // aliases xb
    u16* wqkv = (u16*)(ws + 14180352);                 //  3,538,944 (absorbs OOB)
    u16* wprj = (u16*)(ws + 17719296);                 //  1,179,648
    u16* Qg   = (u16*)(ws + 18898944);                 // 15,728,640
    u16* Kg   = (u16*)(ws + 34627584);                 // 15,728,640
    u16* Vtg  = (u16*)(ws + 50356224);                 // 15,728,640 -> 66,084,864
    // No Vtg memset: pad keys get P = exp2(-1e30-M) = 0 exactly; 0*finite = 0.

    k_prep<<<2048, 256, 0, stream>>>(x, W_qkv, W_proj, xb, wqkv, wprj);

    k_gemm<0, 18><<<18 * 73, 256, 0, stream>>>(xb, wqkv, Qg, Kg, Vtg,
                                               nullptr, nullptr);
    k_attn<<<1728, 256, 0, stream>>>(Qg, Kg, Vtg, coef, Og);
    k_attn_last<<<192, 256, 0, stream>>>(Qg, Kg, Vtg, coef, Og);
    k_gemm<1, 6><<<6 * 73, 256, 0, stream>>>(Og, wprj, nullptr, nullptr,
                                             nullptr, out, b_proj);
}

// Round 11
// 175.339 us; speedup vs baseline: 1.6289x; 1.6289x over previous
//
#include <hip/hip_runtime.h>

// PolyRPE attention, MI355X gfx950.
// prep (cvt + LDS-tiled transposes) -> QKV GEMM (128x128, BK=32, 5-buffer
// gl_lds, prefetch dist 4, counted vmcnt(12), 40KB LDS -> 4 blocks/CU,
// T2 swizzle, T1 XCD grid) -> fused flash attention (4 blocks/CU, P overlay,
// 1 barrier/tile) -> proj GEMM (same pipeline).
//
// Dims: B=16, N=577 (pad 640), C=768, h=12, d=64, K=768, 3C=2304.

using u16 = unsigned short;
using u32 = unsigned int;

typedef __bf16 bf16x8 __attribute__((ext_vector_type(8)));
typedef float f32x4 __attribute__((ext_vector_type(4)));

__device__ inline u16 f2bf(float f) {
    u32 u = __builtin_bit_cast(u32, f);
    u32 r = u + 0x7fffu + ((u >> 16) & 1u);   // RNE
    return (u16)(r >> 16);
}
__device__ inline float bf2f(u16 x) {
    return __builtin_bit_cast(float, (u32)x << 16);
}

__device__ inline f32x4 mfma16(bf16x8 a, bf16x8 b, f32x4 c) {
    return __builtin_amdgcn_mfma_f32_16x16x32_bf16(a, b, c, 0, 0, 0);
}

__device__ inline float fexp2(float x) { return __builtin_amdgcn_exp2f(x); }

// bijective XCD chunk remap (m204)
__device__ inline int xcd_remap(int bid, int nwg) {
    const int q = nwg >> 3, r = nwg & 7;
    const int xcd = bid & 7, idx = bid >> 3;
    return (xcd < r ? xcd * (q + 1) : r * (q + 1) + (xcd - r) * q) + idx;
}

// 16-lane (DPP-row) reductions.
__device__ inline float dpp_max16(float v) {
    int x;
    x = __builtin_amdgcn_update_dpp(0, __builtin_bit_cast(int, v), 0xB1, 0xF, 0xF, true);
    v = fmaxf(v, __builtin_bit_cast(float, x));
    x = __builtin_amdgcn_update_dpp(0, __builtin_bit_cast(int, v), 0x4E, 0xF, 0xF, true);
    v = fmaxf(v, __builtin_bit_cast(float, x));
    x = __builtin_amdgcn_update_dpp(0, __builtin_bit_cast(int, v), 0x124, 0xF, 0xF, true);
    v = fmaxf(v, __builtin_bit_cast(float, x));
    x = __builtin_amdgcn_update_dpp(0, __builtin_bit_cast(int, v), 0x128, 0xF, 0xF, true);
    v = fmaxf(v, __builtin_bit_cast(float, x));
    return v;
}
__device__ inline float dpp_sum16(float v) {
    int x;
    x = __builtin_amdgcn_update_dpp(0, __builtin_bit_cast(int, v), 0xB1, 0xF, 0xF, true);
    v += __builtin_bit_cast(float, x);
    x = __builtin_amdgcn_update_dpp(0, __builtin_bit_cast(int, v), 0x4E, 0xF, 0xF, true);
    v += __builtin_bit_cast(float, x);
    x = __builtin_amdgcn_update_dpp(0, __builtin_bit_cast(int, v), 0x124, 0xF, 0xF, true);
    v += __builtin_bit_cast(float, x);
    x = __builtin_amdgcn_update_dpp(0, __builtin_bit_cast(int, v), 0x128, 0xF, 0xF, true);
    v += __builtin_bit_cast(float, x);
    return v;
}

#define GLOAD_LDS16(g, l)                                                          \
    __builtin_amdgcn_global_load_lds((const __attribute__((address_space(1))) u32*)(g), \
                                     (__attribute__((address_space(3))) u32*)(l), 16, 0, 0)

#define BAR()     asm volatile("s_barrier" ::: "memory")
#define WAITV12() asm volatile("s_waitcnt vmcnt(12)" ::: "memory")
#define WAITV8()  asm volatile("s_waitcnt vmcnt(8)" ::: "memory")
#define WAITV4()  asm volatile("s_waitcnt vmcnt(4)" ::: "memory")
#define WAITV0()  asm volatile("s_waitcnt vmcnt(0)" ::: "memory")

// ---------------- prep ----------------
// blocks 0..575: LDS-tiled 64x64 transposes (432 wqkv + 144 wprj)
// blocks 576..2047: x fp32 -> bf16 (vectorized)
__global__ void k_prep(const float* __restrict__ x, const float* __restrict__ Wq,
                       const float* __restrict__ Wp, u16* __restrict__ xb,
                       u16* __restrict__ wqkv, u16* __restrict__ wprj) {
    const int bid = blockIdx.x;
    const int t = threadIdx.x;
    if (bid < 576) {
        __shared__ float tile[64][65];
        const float* src;
        u16* dst;
        int C, rt, ct;
        if (bid < 432) { src = Wq; dst = wqkv; C = 2304; rt = bid / 36; ct = bid % 36; }
        else { const int b2 = bid - 432; src = Wp; dst = wprj; C = 768; rt = b2 / 12; ct = b2 % 12; }
        const int row0 = rt * 64, col0 = ct * 64;
#pragma unroll
        for (int it = 0; it < 4; ++it) {
            const int row = it * 16 + (t >> 4);
            const float4 v = *(const float4*)&src[(size_t)(row0 + row) * C + col0 + (t & 15) * 4];
            tile[row][(t & 15) * 4 + 0] = v.x;
            tile[row][(t & 15) * 4 + 1] = v.y;
            tile[row][(t & 15) * 4 + 2] = v.z;
            tile[row][(t & 15) * 4 + 3] = v.w;
        }
        __syncthreads();
#pragma unroll
        for (int it = 0; it < 4; ++it) {
            const int oc = it * 16 + (t >> 4);     // input col = output row
            const int orr = (t & 15) * 4;          // input row = output col
            ushort4 o;
            o.x = f2bf(tile[orr + 0][oc]);
            o.y = f2bf(tile[orr + 1][oc]);
            o.z = f2bf(tile[orr + 2][oc]);
            o.w = f2bf(tile[orr + 3][oc]);
            *(ushort4*)&dst[(size_t)(col0 + oc) * 768 + row0 + orr] = o;
        }
    } else {
        const int n4 = 9232 * 768 / 4;
        const int stride = (2048 - 576) * 256;
        for (int i = (bid - 576) * 256 + t; i < n4; i += stride) {
            float4 v = ((const float4*)x)[i];
            ushort4 o;
            o.x = f2bf(v.x); o.y = f2bf(v.y); o.z = f2bf(v.z); o.w = f2bf(v.w);
            ((ushort4*)xb)[i] = o;
        }
    }
}

// ---------------- GEMM (swizzle: chunk' = chunk ^ ((row>>1)&3)) --------------
// Buffer: A[128][32] (elems 0..4095) then B[128][32] (elems 4096..8191).
__device__ inline void stageAB(const u16* __restrict__ Ag, const u16* __restrict__ Bg,
                               u16* L, int t) {
#pragma unroll
    for (int c = 0; c < 2; ++c) {
        const int p = c * 256 + t;
        const int row = p >> 2, ch = p & 3;
        const int src = row * 768 + ((ch ^ ((row >> 1) & 3)) * 8);
        GLOAD_LDS16(Ag + src, L + p * 8);
        GLOAD_LDS16(Bg + src, L + 4096 + p * 8);
    }
}
__device__ inline bf16x8 ldfrag32(const u16* base, int row, int slot) {
    return *(const bf16x8*)(base + row * 32 + ((slot ^ ((row >> 1) & 3)) * 8));
}

// C[M x N] = A[M x 768] * Bw^T, Bw [N][768] bf16. 128x128 tile, BK=32,
// 4 waves 2x2, 5-buffer gl_lds pipeline, prefetch dist 4, counted vmcnt(12).
// 40KB LDS -> 4 blocks/CU (16 waves). 1-D grid, T1 XCD chunking, n-panel
// fastest (A-strip L2 reuse). NB = N-tiles.
// MODE 0: QKV scatter -> Q/K [bh][640][64], Vt [bh][64][640]; MODE 1: fp32+bias.
template <int MODE, int NB>
__launch_bounds__(256, 4)
__global__ void k_gemm(const u16* __restrict__ A, const u16* __restrict__ Bw,
                       u16* __restrict__ q_out, u16* __restrict__ k_out,
                       u16* __restrict__ v_out,
                       float* __restrict__ f_out, const float* __restrict__ bias) {
    constexpr int NT = 24;                    // 768/32
    constexpr int M = 9232;
    const int wgid = xcd_remap(blockIdx.x, gridDim.x);
    const int mbase = (wgid / NB) * 128;
    const int nbase = (wgid - (wgid / NB) * NB) * 128;
    __shared__ alignas(16) u16 lds[5][8192];  // 40 KB -> 4 blocks/CU
    const int t = threadIdx.x;
    const int lane = t & 63, w = t >> 6;
    const int lr = lane & 15, lg = lane >> 4;
    const int wrow = (w >> 1) * 64, wcol = (w & 1) * 64;
    const u16* Ag = A + (size_t)mbase * 768;
    const u16* Bg = Bw + (size_t)nbase * 768;
    f32x4 acc[4][4] = {};

    stageAB(Ag, Bg, &lds[0][0], t);
    stageAB(Ag + 32, Bg + 32, &lds[1][0], t);
    stageAB(Ag + 64, Bg + 64, &lds[2][0], t);
    stageAB(Ag + 96, Bg + 96, &lds[3][0], t);
    WAITV12();          // tile 0 resident; tiles 1..3 in flight
    BAR();

    int cb = 0;
    for (int kt = 0; kt < NT; ++kt) {
        const u16* Lc = &lds[cb][0];
        if (kt + 4 < NT) {
            const int nb = (cb == 0) ? 4 : cb - 1;   // (kt+4)%5
            stageAB(Ag + (kt + 4) * 32, Bg + (kt + 4) * 32, &lds[nb][0], t);
        }
        bf16x8 af[4], bv[4];
#pragma unroll
        for (int i = 0; i < 4; ++i)
            af[i] = ldfrag32(Lc, wrow + i * 16 + lr, lg);
#pragma unroll
        for (int j = 0; j < 4; ++j)
            bv[j] = ldfrag32(Lc + 4096, wcol + j * 16 + lr, lg);
        __builtin_amdgcn_s_setprio(1);
#pragma unroll
        for (int i = 0; i < 4; ++i)
#pragma unroll
            for (int j = 0; j < 4; ++j)
                acc[i][j] = mfma16(af[i], bv[j], acc[i][j]);
        __builtin_amdgcn_s_setprio(0);
        if (kt + 1 < NT) {
            if (kt < NT - 4)       { WAITV12(); }  // tiles kt+2..kt+4 in flight
            else if (kt == NT - 4) { WAITV8(); }
            else if (kt == NT - 3) { WAITV4(); }
            else                   { WAITV0(); }
            BAR();
        }
        cb = (cb == 4) ? 0 : cb + 1;
    }

#pragma unroll
    for (int i = 0; i < 4; ++i) {
#pragma unroll
        for (int j = 0; j < 4; ++j) {
            const int col = nbase + wcol + j * 16 + lr;
#pragma unroll
            for (int r = 0; r < 4; ++r) {
                const int row = mbase + wrow + i * 16 + 4 * lg + r;
                if (row < M) {
                    if (MODE == 0) {
                        const int bb = row / 577;
                        const int nn = row - bb * 577;
                        const int tt = col / 768;
                        const int rem = col - tt * 768;
                        const int hh = rem >> 6, dd = rem & 63;
                        const size_t bh = (size_t)bb * 12 + hh;
                        const u16 val = f2bf(acc[i][j][r]);
                        if (tt == 0)      q_out[(bh * 640 + nn) * 64 + dd] = val;
                        else if (tt == 1) k_out[(bh * 640 + nn) * 64 + dd] = val;
                        else              v_out[(bh * 64 + dd) * 640 + nn] = val;
                    } else {
                        f_out[(size_t)row * 768 + col] = acc[i][j][r] + bias[col];
                    }
                }
            }
        }
    }
}

// ---------------- fused attention (q rows 0..575) ----------------
// 33 KB LDS -> 4 blocks/CU. P overlays Vl[cur^1] (dead V buffer); V staging
// rows are wave-owned so post-PV stores only touch the wave's consumed P.
__launch_bounds__(256, 4)
__global__ void k_attn(const u16* __restrict__ Qg, const u16* __restrict__ Kg,
                       const u16* __restrict__ Vtg, const float* __restrict__ coef,
                       u16* __restrict__ Og) {
    const int wgid = xcd_remap(blockIdx.x, gridDim.x);   // 1728 = 8*216 exact
    const int bh = wgid / 9;            // consecutive wgids share bh (XCD-local K/V)
    const int qt = wgid - bh * 9;       // 0..8
    const int b = bh / 12, h = bh - b * 12;
    const int t = threadIdx.x;
    const int lane = t & 63, w = t >> 6;
    const int lr = lane & 15, lg = lane >> 4;
    __shared__ alignas(16) u16 Kl[2][4096];
    __shared__ alignas(16) u16 Vl[2][4096];
    __shared__ float lut[48];

    {   // LUT: poly(dist)*log2e for dist<=46; lut[47]=0 catches CLS sentinels
        const float l2e = 1.4426950408889634f;
        const float c0 = coef[h * 4 + 0] * l2e, c1 = coef[h * 4 + 1] * l2e,
                    c2 = coef[h * 4 + 2] * l2e, c3 = coef[h * 4 + 3] * l2e;
        if (t < 48) {
            const float d = (float)t;
            lut[t] = (t <= 46) ? (((c3 * d + c2) * d + c1) * d + c0) : 0.f;
        }
    }

    const int qrow0 = qt * 64 + w * 16;
    const u16* qp = Qg + ((size_t)bh * 640 + qrow0 + lr) * 64;
    const bf16x8 qa0 = *(const bf16x8*)(qp + lg * 8);
    const bf16x8 qa1 = *(const bf16x8*)(qp + 32 + lg * 8);

    float gi[4], gj[4];
#pragma unroll
    for (int r = 0; r < 4; ++r) {
        const int n = qrow0 + 4 * lg + r;
        if (n == 0) { gi[r] = 100.f; gj[r] = 0.f; }
        else {
            const int nm1 = n - 1;
            const int qi = nm1 / 24;
            gi[r] = (float)qi;
            gj[r] = (float)(nm1 - qi * 24);
        }
    }

    float M[4], L[4];
#pragma unroll
    for (int r = 0; r < 4; ++r) { M[r] = -3e38f; L[r] = 0.f; }
    f32x4 acco[4] = {};
    const float scale2 = 0.125f * 1.4426950408889634f;
    const int ch0 = ((lg ^ (lr & 7))) * 8;      // swizzled read chunk (elems)

    const u16* Ksb = Kg + (size_t)bh * 640 * 64;
    const u16* Vsb = Vtg + (size_t)bh * 64 * 640;
    // K staging: rows t>>3 (any order; Kl[cur^1] unread this tile)
    const int pr0 = t >> 3, pc0 = t & 7;
    const int pr1 = (256 + t) >> 3, pc1 = (256 + t) & 7;
    const int kd0 = pr0 * 64 + ((pc0 ^ (pr0 & 7)) * 8);
    const int kd1 = pr1 * 64 + ((pc1 ^ (pr1 & 7)) * 8);
    // V staging: wave-owned rows (wave w -> rows 16w..16w+15)
    const int vr0 = 16 * w + (lane >> 3), vc = lane & 7;
    const int vr1 = vr0 + 8;
    const int vd0 = vr0 * 64 + ((vc ^ (vr0 & 7)) * 8);
    const int vd1 = vr1 * 64 + ((vc ^ (vr1 & 7)) * 8);

    {   // prologue: tile 0 -> regs -> LDS buf 0
        uint4 k0 = *(const uint4*)(Ksb + pr0 * 64 + pc0 * 8);
        uint4 k1 = *(const uint4*)(Ksb + pr1 * 64 + pc1 * 8);
        uint4 v0 = *(const uint4*)(Vsb + (size_t)vr0 * 640 + vc * 8);
        uint4 v1 = *(const uint4*)(Vsb + (size_t)vr1 * 640 + vc * 8);
        *(uint4*)(&Kl[0][kd0]) = k0;
        *(uint4*)(&Kl[0][kd1]) = k1;
        *(uint4*)(&Vl[0][vd0]) = v0;
        *(uint4*)(&Vl[0][vd1]) = v1;
    }
    __syncthreads();
    int cur = 0;

    for (int kt = 0; kt < 9; ++kt) {
        // issue next K/V tile's loads early (incl. tail tile 9)
        const u16* Ks = Ksb + (size_t)(kt + 1) * 64 * 64;
        const u16* Vs = Vsb + (size_t)(kt + 1) * 64;
        const uint4 nk0 = *(const uint4*)(Ks + pr0 * 64 + pc0 * 8);
        const uint4 nk1 = *(const uint4*)(Ks + pr1 * 64 + pc1 * 8);
        const uint4 nv0 = *(const uint4*)(Vs + (size_t)vr0 * 640 + vc * 8);
        const uint4 nv1 = *(const uint4*)(Vs + (size_t)vr1 * 640 + vc * 8);

        const u16* Kc = &Kl[cur][0];
        const u16* Vc = &Vl[cur][0];
        u16* pw = &Vl[cur ^ 1][w * 1024];    // P overlay: wave-owned 16x64

        // S = Q K^T
        f32x4 sac[4];
        __builtin_amdgcn_s_setprio(1);
#pragma unroll
        for (int cb = 0; cb < 4; ++cb) {
            const int row = cb * 16 + lr;
            const bf16x8 kb0 = *(const bf16x8*)(Kc + row * 64 + ch0);
            const bf16x8 kb1 = *(const bf16x8*)(Kc + row * 64 + (ch0 ^ 32));
            f32x4 z = {};
            z = mfma16(qa0, kb0, z);
            sac[cb] = mfma16(qa1, kb1, z);
        }
        __builtin_amdgcn_s_setprio(0);

        float s[4][4], tm[4];
#pragma unroll
        for (int r = 0; r < 4; ++r) tm[r] = -3e38f;
#pragma unroll
        for (int cb = 0; cb < 4; ++cb) {
            const int m = kt * 64 + cb * 16 + lr;
            float ci, cj;
            if (m == 0) { ci = 200.f; cj = 0.f; }
            else {
                const int mm1 = m - 1;
                const int pi = mm1 / 24;
                ci = (float)pi;
                cj = (float)(mm1 - pi * 24);
            }
#pragma unroll
            for (int r = 0; r < 4; ++r) {
                const float df = fabsf(gi[r] - ci) + fabsf(gj[r] - cj);
                const int idx = min((int)df, 47);
                const float v = fmaf(sac[cb][r], scale2, lut[idx]);
                s[cb][r] = v;
                tm[r] = fmaxf(tm[r], v);
            }
        }
#pragma unroll
        for (int r = 0; r < 4; ++r) tm[r] = dpp_max16(tm[r]);

        float over = tm[0] - M[0];
        over = fmaxf(over, tm[1] - M[1]);
        over = fmaxf(over, tm[2] - M[2]);
        over = fmaxf(over, tm[3] - M[3]);
        if (__any(over > 11.5f)) {
#pragma unroll
            for (int r = 0; r < 4; ++r) {
                const float Mn = fmaxf(M[r], tm[r]);
                const float a = fexp2(M[r] - Mn);
                L[r] *= a;
                acco[0][r] *= a; acco[1][r] *= a;
                acco[2][r] *= a; acco[3][r] *= a;
                M[r] = Mn;
            }
        }

        // P -> overlay (swizzled): row'=4lg+r, chunk=2cb+(lr>>3), elem=lr&7
#pragma unroll
        for (int cb = 0; cb < 4; ++cb)
#pragma unroll
            for (int r = 0; r < 4; ++r) {
                const float p = fexp2(s[cb][r] - M[r]);
                L[r] += p;
                const int rw = 4 * lg + r;
                pw[rw * 64 + (((2 * cb + (lr >> 3)) ^ (rw & 7)) * 8) + (lr & 7)] = f2bf(p);
            }
        const bf16x8 pa0 = *(const bf16x8*)(pw + lr * 64 + ch0);
        const bf16x8 pa1 = *(const bf16x8*)(pw + lr * 64 + (ch0 ^ 32));
        __builtin_amdgcn_s_setprio(1);
#pragma unroll
        for (int f = 0; f < 4; ++f) {
            const int vrow = f * 16 + lr;
            const bf16x8 vb0 = *(const bf16x8*)(Vc + vrow * 64 + ch0);
            const bf16x8 vb1 = *(const bf16x8*)(Vc + vrow * 64 + (ch0 ^ 32));
            acco[f] = mfma16(pa0, vb0, acco[f]);
            acco[f] = mfma16(pa1, vb1, acco[f]);
        }
        __builtin_amdgcn_s_setprio(0);

        // land prefetched tile: K anywhere in Kl[cur^1] (unread); V only into
        // this wave's own rows (its P was consumed above; per-wave DS order)
        *(uint4*)(&Kl[cur ^ 1][kd0]) = nk0;
        *(uint4*)(&Kl[cur ^ 1][kd1]) = nk1;
        *(uint4*)(&Vl[cur ^ 1][vd0]) = nv0;
        *(uint4*)(&Vl[cur ^ 1][vd1]) = nv1;
        __syncthreads();
        cur ^= 1;
    }

    {   // ---- peeled tail tile (kt=9): only key m=576 (cb=0, lr==0) valid ----
        const u16* Kc = &Kl[cur][0];
        const u16* Vc = &Vl[cur][0];
        u16* pw = &Vl[cur ^ 1][w * 1024];
        const bf16x8 kb0 = *(const bf16x8*)(Kc + lr * 64 + ch0);
        const bf16x8 kb1 = *(const bf16x8*)(Kc + lr * 64 + (ch0 ^ 32));
        f32x4 z = {};
        z = mfma16(qa0, kb0, z);
        const f32x4 sac0 = mfma16(qa1, kb1, z);

        float s0[4], tm[4];
#pragma unroll
        for (int r = 0; r < 4; ++r) {
            const float df = fabsf(gi[r] - 23.f) + fabsf(gj[r] - 23.f);
            float v = fmaf(sac0[r], scale2, lut[min((int)df, 47)]);
            v = (lr == 0) ? v : -1e30f;
            s0[r] = v;
            tm[r] = dpp_max16(v);
        }
        float over = tm[0] - M[0];
        over = fmaxf(over, tm[1] - M[1]);
        over = fmaxf(over, tm[2] - M[2]);
        over = fmaxf(over, tm[3] - M[3]);
        if (__any(over > 11.5f)) {
#pragma unroll
            for (int r = 0; r < 4; ++r) {
                const float Mn = fmaxf(M[r], tm[r]);
                const float a = fexp2(M[r] - Mn);
                L[r] *= a;
                acco[0][r] *= a; acco[1][r] *= a;
                acco[2][r] *= a; acco[3][r] *= a;
                M[r] = Mn;
            }
        }
#pragma unroll
        for (int cb = 0; cb < 4; ++cb)
#pragma unroll
            for (int r = 0; r < 4; ++r) {
                const float p = (cb == 0) ? fexp2(s0[r] - M[r]) : 0.f;
                L[r] += p;
                const int rw = 4 * lg + r;
                pw[rw * 64 + (((2 * cb + (lr >> 3)) ^ (rw & 7)) * 8) + (lr & 7)] = f2bf(p);
            }
        const bf16x8 pa0 = *(const bf16x8*)(pw + lr * 64 + ch0);
#pragma unroll
        for (int f = 0; f < 4; ++f) {
            const int vrow = f * 16 + lr;
            const bf16x8 vb0 = *(const bf16x8*)(Vc + vrow * 64 + ch0);
            acco[f] = mfma16(pa0, vb0, acco[f]);
        }
    }

    float inv[4];
#pragma unroll
    for (int r = 0; r < 4; ++r) inv[r] = __builtin_amdgcn_rcpf(dpp_sum16(L[r]));
#pragma unroll
    for (int f = 0; f < 4; ++f)
#pragma unroll
        for (int r = 0; r < 4; ++r) {
            const int n = qrow0 + 4 * lg + r;     // <= 575, always valid
            Og[((size_t)b * 577 + n) * 768 + h * 64 + f * 16 + lr] =
                f2bf(acco[f][r] * inv[r]);
        }
}

// ---------------- attention for the single leftover row n=576 ----------------
__launch_bounds__(256)
__global__ void k_attn_last(const u16* __restrict__ Qg, const u16* __restrict__ Kg,
                            const u16* __restrict__ Vtg, const float* __restrict__ coef,
                            u16* __restrict__ Og) {
    const int bh = blockIdx.x;
    const int b = bh / 12, h = bh - b * 12;
    const int t = threadIdx.x;
    const int lane = t & 63, w = t >> 6;
    __shared__ float qs[64];
    __shared__ float ps[640];
    __shared__ float red[4];
    __shared__ float opart[4][64];
    const float l2e = 1.4426950408889634f;
    const float c0 = coef[h * 4 + 0] * l2e, c1 = coef[h * 4 + 1] * l2e,
                c2 = coef[h * 4 + 2] * l2e, c3 = coef[h * 4 + 3] * l2e;
    const float scale2 = 0.125f * l2e;

    if (t < 64) qs[t] = bf2f(Qg[((size_t)bh * 640 + 576) * 64 + t]);
    __syncthreads();

    float sv[3];
#pragma unroll
    for (int u = 0; u < 3; ++u) {
        const int k = t + u * 256;
        float s = -3e38f;
        if (k < 577) {
            const u16* kp = Kg + ((size_t)bh * 640 + k) * 64;
            float acc = 0.f;
            for (int j = 0; j < 64; ++j) acc += qs[j] * bf2f(kp[j]);
            float rv = 0.f;
            if (k >= 1) {
                const int km1 = k - 1;
                const int ki = km1 / 24;
                const float d = fabsf(23.f - (float)ki) + fabsf(23.f - (float)(km1 - ki * 24));
                rv = ((c3 * d + c2) * d + c1) * d + c0;
            }
            s = fmaf(acc, scale2, rv);
        }
        sv[u] = s;
    }
    float v = fmaxf(fmaxf(sv[0], sv[1]), sv[2]);
    v = fmaxf(v, __shfl_xor(v, 1));  v = fmaxf(v, __shfl_xor(v, 2));
    v = fmaxf(v, __shfl_xor(v, 4));  v = fmaxf(v, __shfl_xor(v, 8));
    v = fmaxf(v, __shfl_xor(v, 16)); v = fmaxf(v, __shfl_xor(v, 32));
    if (lane == 0) red[w] = v;
    __syncthreads();
    const float Mx = fmaxf(fmaxf(red[0], red[1]), fmaxf(red[2], red[3]));

    float lsum = 0.f;
#pragma unroll
    for (int u = 0; u < 3; ++u) {
        const int k = t + u * 256;
        const float p = (k < 577) ? fexp2(sv[u] - Mx) : 0.f;
        if (k < 640) ps[k] = p;
        lsum += p;
    }
    lsum += __shfl_xor(lsum, 1);  lsum += __shfl_xor(lsum, 2);
    lsum += __shfl_xor(lsum, 4);  lsum += __shfl_xor(lsum, 8);
    lsum += __shfl_xor(lsum, 16); lsum += __shfl_xor(lsum, 32);
    __syncthreads();
    if (lane == 0) red[w] = lsum;
    __syncthreads();
    const float Lx = red[0] + red[1] + red[2] + red[3];

    const int d = t & 63, qd = t >> 6;
    const u16* vp = Vtg + ((size_t)bh * 64 + d) * 640;
    float o = 0.f;
    for (int k = qd * 160; k < qd * 160 + 160; ++k) o += ps[k] * bf2f(vp[k]);
    opart[qd][d] = o;
    __syncthreads();
    if (t < 64) {
        const float oo = (opart[0][t] + opart[1][t] + opart[2][t] + opart[3][t]) / Lx;
        Og[((size_t)b * 577 + 576) * 768 + h * 64 + t] = f2bf(oo);
    }
}

// ---------------- launch ----------------
extern "C" void kernel_launch(void* const* d_in, const int* in_sizes, int n_in,
                              void* d_out, int out_size, void* d_ws, size_t ws_size,
                              hipStream_t stream) {
    const float* x      = (const float*)d_in[0];
    const float* W_qkv  = (const float*)d_in[1];
    const float* W_proj = (const float*)d_in[2];
    const float* b_proj = (const float*)d_in[3];
    const float* coef   = (const float*)d_in[4];
    float* out = (float*)d_out;
    char* ws = (char*)d_ws;

    // ws layout with lifetime aliasing (66.1 MB total):
    //   xb : live prep..gemm0  |  Og : live attn..gemm1 (ALIASES xb)
    u16* xb   = (u16*)(ws + 0);                        // 14,180,352
    u16* Og   = (u16*)(ws + 0);                        // aliases xb
    u16* wqkv = (u16*)(ws + 14180352);                 //  3,538,944 (absorbs OOB)
    u16* wprj = (u16*)(ws + 17719296);                 //  1,179,648
    u16* Qg   = (u16*)(ws + 18898944);                 // 15,728,640
    u16* Kg   = (u16*)(ws + 34627584);                 // 15,728,640
    u16* Vtg  = (u16*)(ws + 50356224);                 // 15,728,640 -> 66,084,864
    // No Vtg memset: pad keys get P = exp2(-1e30-M) = 0 exactly; 0*finite = 0.

    k_prep<<<2048, 256, 0, stream>>>(x, W_qkv, W_proj, xb, wqkv, wprj);

    k_gemm<0, 18><<<18 * 73, 256, 0, stream>>>(xb, wqkv, Qg, Kg, Vtg,
                                               nullptr, nullptr);
    k_attn<<<1728, 256, 0, stream>>>(Qg, Kg, Vtg, coef, Og);
    k_attn_last<<<192, 256, 0, stream>>>(Qg, Kg, Vtg, coef, Og);
    k_gemm<1, 6><<<6 * 73, 256, 0, stream>>>(Og, wprj, nullptr, nullptr,
                                             nullptr, out, b_proj);
}